// Round 9
// baseline (45.393 us; speedup 1.0000x reference)
//
#include <hip/hip_runtime.h>
#include <hip/hip_bf16.h>

// SimLoss: loss = (1/n) [ sum_r log(1 + sum_{j!=r} exp(cos(r,j))) - 2*sum_m cos(m, m+4096) ]
// n=8192, d=256. R9 = R8 + the missing mid-tile barrier (R8's NaN was a cross-wave
// race: epilogue cs/dsh overlay wrote into buffer pb while other waves still
// ds_read B fragments from pb). Structure:
//   520 blocks x 4 consecutive triangle tiles;
//   A panel in registers (global/L2, reload on bi-change, issued BEFORE prefetch);
//   B tile (32KB) double-buffered, stage(t+1) at top of tile t (covered by compute);
//   epilogue scratch overlays consumed B buffer AFTER a barrier; 3 barriers/tile.
// MX-fp8 e4m3 (prescaled x16, unit scales), mfma_scale 16x16x128, swapped operands.
// Workspace (~4.25 MB):
//   xq    : u8  [8192*256]  @ 0         (2,097,152 B)  fp8 e4m3 of 16*x/||x||
//   norms : f32 [8192]      @ 2,097,152 (32 KB)
//   dots  : f32 [4096]      @ 2,129,920 (16 KB)
//   part  : f32 [64*8192]   @ 2,146,304 (2 MB)
//   bsum  : f32 [32]        @ 4,243,456

#define N_ROWS 8192
#define HALF   4096
#define DDIM   256
#define NBLK   64

typedef unsigned int   u32;
typedef unsigned char  u8;
typedef __attribute__((ext_vector_type(4))) float f32x4;
typedef __attribute__((ext_vector_type(4))) int   i32x4;
typedef __attribute__((ext_vector_type(8))) int   i32x8;

// float -> OCP e4m3fn (RNE). Assumes |f| <= 448, finite.
__device__ __forceinline__ u32 f2e4m3(float f) {
    const u32 u = __builtin_bit_cast(u32, f);
    const u32 s = (u >> 24) & 0x80u;
    const float af = fabsf(f);
    if (af < 0.015625f) {                        // subnormal: step 2^-9
        const int mi = (int)rintf(af * 512.0f);
        return s | (u32)mi;
    }
    u32 keep = (u & 0x7FFFFFFFu) >> 20;          // exp(8)|mant(3)
    const u32 rem = u & 0xFFFFFu;
    keep += (rem > 0x80000u) || (rem == 0x80000u && (keep & 1u));
    const int ef = (int)(keep >> 3) - 120;       // -127+7
    return s | ((u32)ef << 3) | (keep & 7u);
}

// Kernel 1: blocks [0,2048): norms + fp8 rows (prescaled x16). [2048,3072): exact pair dots.
__global__ __launch_bounds__(256) void prep_kernel(const float* __restrict__ x,
                                                   u8* __restrict__ xq,
                                                   float* __restrict__ norms,
                                                   float* __restrict__ dots) {
    const int w = threadIdx.x >> 6, l = threadIdx.x & 63;
    if (blockIdx.x < 2048) {
        const int row = blockIdx.x * 4 + w;
        const float4 v = reinterpret_cast<const float4*>(x + (size_t)row * DDIM)[l];
        float sq = v.x * v.x + v.y * v.y + v.z * v.z + v.w * v.w;
#pragma unroll
        for (int off = 1; off < 64; off <<= 1) sq += __shfl_xor(sq, off);
        const float norm = sqrtf(sq);
        if (l == 0) norms[row] = norm;
        const float rs = 16.0f / norm;
        const u32 pk = f2e4m3(v.x * rs) | (f2e4m3(v.y * rs) << 8) |
                       (f2e4m3(v.z * rs) << 16) | (f2e4m3(v.w * rs) << 24);
        reinterpret_cast<u32*>(xq + (size_t)row * DDIM)[l] = pk;
    } else {
        const int m = (blockIdx.x - 2048) * 4 + w;
        const float4 a = reinterpret_cast<const float4*>(x + (size_t)m * DDIM)[l];
        const float4 b = reinterpret_cast<const float4*>(x + (size_t)(m + HALF) * DDIM)[l];
        float s = a.x * b.x + a.y * b.y + a.z * b.z + a.w * b.w;
#pragma unroll
        for (int off = 1; off < 64; off <<= 1) s += __shfl_xor(s, off);
        if (l == 0) dots[m] = s;
    }
}

// Kernel 2: tile-stream symmetric fused Gram (MX-fp8). 520 blocks x 4 tiles.
__global__ __launch_bounds__(256, 2) void gram_kernel(const u8* __restrict__ xq,
                                                      float* __restrict__ part) {
    const int tstart = blockIdx.x * 4;
    int bi = (int)(0.5f * (129.0f - sqrtf(16641.0f - 8.0f * (float)tstart)));
    if (bi > 0 && bi * (129 - bi) / 2 > tstart) --bi;
    if ((bi + 1) * (129 - (bi + 1)) / 2 <= tstart) ++bi;
    int bj = bi + (tstart - bi * (129 - bi) / 2);

    __shared__ __align__(16) u8 smem[65536];   // B double-buffer, 32KB each

    const int tid = threadIdx.x;
    const int w = tid >> 6, l = tid & 63;
    const int wr = w >> 1, wc = w & 1;

    // staging pattern per 16KB chunk (128 rows x 128 B): lane l -> row l>>3,
    // LDS granule l&7; source granule XOR-swizzled: LDS[row][g] = glob[row][g^(row&7)]
    const int krow = l >> 3;
    const int kbyte = ((l & 7) ^ krow) * 16;
    const int r7 = l & 7;
    const int kq2 = (l >> 4) * 2;

    auto stageB = [&](int c0, int bufsel) {    // full 32KB tile (both ks chunks)
#pragma unroll
        for (int ks = 0; ks < 2; ++ks)
#pragma unroll
            for (int i = 0; i < 4; ++i) {
                const int rr = w * 32 + i * 8;
                const u8* g = xq + (size_t)(c0 + rr + krow) * DDIM + ks * 128 + kbyte;
                __builtin_amdgcn_global_load_lds(
                    (const __attribute__((address_space(1))) u32*)g,
                    (__attribute__((address_space(3))) u32*)
                        (smem + bufsel * 32768 + ks * 16384 + rr * 128), 16, 0, 0);
            }
    };

    i32x8 afr[4][2];      // A-panel fragments (row panel bi), in registers
    f32x4 acc[4][4];
    int cura = -1;
    int pb = 0;

    stageB(bj * 128, 0);  // prologue (only exposed stage of the block)

    for (int tt = 0; tt < 4; ++tt) {
        const bool diagblk = (bi == bj);
        const int r0 = bi * 128, c0 = bj * 128;
        int nbi = bi, nbj = bj + 1;
        if (nbj == NBLK) { nbi = bi + 1; nbj = nbi; }

        __syncthreads();                       // B(tt) ready in buf pb

        if (bi != cura) {                      // A regs from global (L2); BEFORE prefetch
            cura = bi;
#pragma unroll
            for (int n = 0; n < 4; ++n)
#pragma unroll
                for (int ks = 0; ks < 2; ++ks) {
                    const u8* ap = xq + (size_t)(r0 + wr * 64 + n * 16 + (l & 15)) * DDIM
                                      + ks * 128 + (l >> 4) * 32;
                    const i32x4 lo = *reinterpret_cast<const i32x4*>(ap);
                    const i32x4 hi = *reinterpret_cast<const i32x4*>(ap + 16);
                    afr[n][ks][0] = lo[0]; afr[n][ks][1] = lo[1];
                    afr[n][ks][2] = lo[2]; afr[n][ks][3] = lo[3];
                    afr[n][ks][4] = hi[0]; afr[n][ks][5] = hi[1];
                    afr[n][ks][6] = hi[2]; afr[n][ks][7] = hi[3];
                }
        }
        if (tt < 3) stageB(nbj * 128, pb ^ 1); // prefetch next B; lands under compute

        const f32x4 vzero = {0.f, 0.f, 0.f, 0.f};
#pragma unroll
        for (int m = 0; m < 4; ++m)
#pragma unroll
            for (int n = 0; n < 4; ++n) acc[m][n] = vzero;

#pragma unroll
        for (int ks = 0; ks < 2; ++ks) {
            const u8* Bbase = smem + pb * 32768 + ks * 16384;
            i32x8 bfr[4];
#pragma unroll
            for (int m = 0; m < 4; ++m) {
                const u8* rowp = Bbase + (wc * 64 + m * 16 + (l & 15)) * 128;
                const i32x4 lo = *reinterpret_cast<const i32x4*>(rowp + ((kq2 ^ r7) << 4));
                const i32x4 hi = *reinterpret_cast<const i32x4*>(rowp + (((kq2 + 1) ^ r7) << 4));
                bfr[m][0] = lo[0]; bfr[m][1] = lo[1]; bfr[m][2] = lo[2]; bfr[m][3] = lo[3];
                bfr[m][4] = hi[0]; bfr[m][5] = hi[1]; bfr[m][6] = hi[2]; bfr[m][7] = hi[3];
            }
            // swapped operands: D col (lane&15) = A-row r, D row axis = B-row j
#pragma unroll
            for (int n = 0; n < 4; ++n)
#pragma unroll
                for (int m = 0; m < 4; ++m)
                    acc[m][n] = __builtin_amdgcn_mfma_scale_f32_16x16x128_f8f6f4(
                        bfr[m], afr[n][ks], acc[m][n], 0, 0, 0, 0x7F7F7F7F, 0, 0x7F7F7F7F);
        }

        // epilogue (registers): cos = acc/256; exp; diag -> 1.0
        // Layout: r = r0 + wr*64 + n*16 + (l&15); j = c0 + wc*64 + m*16 + (l>>4)*4 + rg
#pragma unroll
        for (int m = 0; m < 4; ++m)
#pragma unroll
            for (int n = 0; n < 4; ++n)
#pragma unroll
                for (int rg = 0; rg < 4; ++rg) {
                    const float e = __expf(acc[m][n][rg] * 0.00390625f);
                    if (diagblk) {
                        const int j_loc = wc * 64 + m * 16 + (l >> 4) * 4 + rg;
                        const int r_loc = wr * 64 + n * 16 + (l & 15);
                        acc[m][n][rg] = (j_loc == r_loc) ? 1.0f : e;
                    } else {
                        acc[m][n][rg] = e;
                    }
                }

        __syncthreads();   // ALL waves' ds_reads of buf pb done -> overlay is safe
                           // (this was the R8 race; prefetch has had full compute to land)

        // scratch overlays the CONSUMED B buffer (pb)
        float* cs  = (float*)(smem + pb * 32768);           // [2 wr][128 j][17] = 17408 B
        float* dsh = (float*)(smem + pb * 32768 + 17408);   // [2 wc][128 r]   =  1024 B

        // row-sums (den): lane-local over m,rg; 2 shuffles across l>>4 groups
#pragma unroll
        for (int n = 0; n < 4; ++n) {
            float s = 0.f;
#pragma unroll
            for (int m = 0; m < 4; ++m)
#pragma unroll
                for (int rg = 0; rg < 4; ++rg) s += acc[m][n][rg];
            s += __shfl_xor(s, 16);
            s += __shfl_xor(s, 32);
            if (l < 16) dsh[wc * 128 + wr * 64 + n * 16 + l] = s;
        }

        // col-sums (off-diag only): per-lane partial over n, staged to LDS
        if (!diagblk) {
#pragma unroll
            for (int m = 0; m < 4; ++m)
#pragma unroll
                for (int rg = 0; rg < 4; ++rg) {
                    const float s = acc[m][0][rg] + acc[m][1][rg] + acc[m][2][rg] + acc[m][3][rg];
                    const int j_loc = wc * 64 + m * 16 + (l >> 4) * 4 + rg;
                    cs[(wr * 128 + j_loc) * 17 + (l & 15)] = s;
                }
        }
        __syncthreads();   // cs/dsh visible

        if (tid < 128) {
            const float den = dsh[tid] + dsh[128 + tid];
            part[(size_t)bj * N_ROWS + r0 + tid] = den;
            if (!diagblk) {
                float c = 0.f;
#pragma unroll
                for (int k = 0; k < 16; ++k)
                    c += cs[tid * 17 + k] + cs[(128 + tid) * 17 + k];
                part[(size_t)bi * N_ROWS + c0 + tid] = c;
            }
        }

        pb ^= 1;
        bi = nbi; bj = nbj;
    }
}

__global__ __launch_bounds__(256) void fin1_kernel(const float* __restrict__ part,
                                                   const float* __restrict__ norms,
                                                   const float* __restrict__ dots,
                                                   float* __restrict__ bsum) {
    const int b = blockIdx.x, t = threadIdx.x;
    const int r = b * 256 + t;
    float den = 0.f;
#pragma unroll 8
    for (int bj = 0; bj < 64; ++bj) den += part[(size_t)bj * N_ROWS + r];
    float local = logf(den);
    if (t < 128) {
        const int m = b * 128 + t;
        local -= 2.0f * dots[m] / (norms[m] * norms[m + HALF]);
    }
#pragma unroll
    for (int off = 1; off < 64; off <<= 1) local += __shfl_xor(local, off);
    __shared__ float wsum[4];
    if ((t & 63) == 0) wsum[t >> 6] = local;
    __syncthreads();
    if (t == 0) bsum[b] = wsum[0] + wsum[1] + wsum[2] + wsum[3];
}

__global__ void fin2_kernel(const float* __restrict__ bsum, float* __restrict__ out) {
    const int t = threadIdx.x;
    float v = (t < 32) ? bsum[t] : 0.f;
#pragma unroll
    for (int off = 1; off < 32; off <<= 1) v += __shfl_xor(v, off);
    if (t == 0) out[0] = v / (float)N_ROWS;
}

extern "C" void kernel_launch(void* const* d_in, const int* in_sizes, int n_in,
                              void* d_out, int out_size, void* d_ws, size_t ws_size,
                              hipStream_t stream) {
    const float* x = (const float*)d_in[0];
    float* out = (float*)d_out;
    char* ws = (char*)d_ws;

    u8*    xq    = (u8*)ws;
    float* norms = (float*)(ws + 2097152);
    float* dots  = (float*)(ws + 2129920);
    float* part  = (float*)(ws + 2146304);
    float* bsum  = (float*)(ws + 4243456);

    prep_kernel<<<3072, 256, 0, stream>>>(x, xq, norms, dots);
    gram_kernel<<<520, 256, 0, stream>>>(xq, part);
    fin1_kernel<<<32, 256, 0, stream>>>(part, norms, dots, bsum);
    fin2_kernel<<<1, 64, 0, stream>>>(bsum, out);
}

// Round 12
// 34.325 us; speedup vs baseline: 1.3224x; 1.3224x over previous
//
#include <hip/hip_runtime.h>
#include <hip/hip_bf16.h>

// SimLoss: loss = (1/n) [ sum_r log(1 + sum_{j!=r} exp(cos(r,j))) - 2*sum_m cos(m, m+4096) ]
// n=8192, d=256. R12 = R4 (best-known-good, 34.1us) + bijective XCD swizzle on the
// triangular block index (2080 = 8*260 exactly). R4 structure: symmetric Gram in
// MX-fp8 (e4m3 prescaled x16, unit scales), mfma_scale 16x16x128, K=256 = 2 staging
// rounds, swapped operands (row-sum lane-local), granule-XOR LDS swizzle.
// Workspace (~4.25 MB):
//   xq    : u8  [8192*256]  @ 0         (2,097,152 B)  fp8 e4m3 of 16*x/||x||
//   norms : f32 [8192]      @ 2,097,152 (32 KB)
//   dots  : f32 [4096]      @ 2,129,920 (16 KB)
//   part  : f32 [64*8192]   @ 2,146,304 (2 MB)
//   bsum  : f32 [32]        @ 4,243,456

#define N_ROWS 8192
#define HALF   4096
#define DDIM   256
#define NBLK   64

typedef unsigned int   u32;
typedef unsigned char  u8;
typedef __attribute__((ext_vector_type(4))) float f32x4;
typedef __attribute__((ext_vector_type(4))) int   i32x4;
typedef __attribute__((ext_vector_type(8))) int   i32x8;

// float -> OCP e4m3fn (RNE). Assumes |f| <= 448, finite.
__device__ __forceinline__ u32 f2e4m3(float f) {
    const u32 u = __builtin_bit_cast(u32, f);
    const u32 s = (u >> 24) & 0x80u;
    const float af = fabsf(f);
    if (af < 0.015625f) {                        // subnormal: step 2^-9
        const int mi = (int)rintf(af * 512.0f);
        return s | (u32)mi;
    }
    u32 keep = (u & 0x7FFFFFFFu) >> 20;          // exp(8)|mant(3)
    const u32 rem = u & 0xFFFFFu;
    keep += (rem > 0x80000u) || (rem == 0x80000u && (keep & 1u));
    const int ef = (int)(keep >> 3) - 120;       // -127+7
    return s | ((u32)ef << 3) | (keep & 7u);
}

// Kernel 1: blocks [0,2048): norms + fp8 rows (prescaled x16). [2048,3072): exact pair dots.
__global__ __launch_bounds__(256) void prep_kernel(const float* __restrict__ x,
                                                   u8* __restrict__ xq,
                                                   float* __restrict__ norms,
                                                   float* __restrict__ dots) {
    const int w = threadIdx.x >> 6, l = threadIdx.x & 63;
    if (blockIdx.x < 2048) {
        const int row = blockIdx.x * 4 + w;
        const float4 v = reinterpret_cast<const float4*>(x + (size_t)row * DDIM)[l];
        float sq = v.x * v.x + v.y * v.y + v.z * v.z + v.w * v.w;
#pragma unroll
        for (int off = 1; off < 64; off <<= 1) sq += __shfl_xor(sq, off);
        const float norm = sqrtf(sq);
        if (l == 0) norms[row] = norm;
        const float rs = 16.0f / norm;
        const u32 pk = f2e4m3(v.x * rs) | (f2e4m3(v.y * rs) << 8) |
                       (f2e4m3(v.z * rs) << 16) | (f2e4m3(v.w * rs) << 24);
        reinterpret_cast<u32*>(xq + (size_t)row * DDIM)[l] = pk;
    } else {
        const int m = (blockIdx.x - 2048) * 4 + w;
        const float4 a = reinterpret_cast<const float4*>(x + (size_t)m * DDIM)[l];
        const float4 b = reinterpret_cast<const float4*>(x + (size_t)(m + HALF) * DDIM)[l];
        float s = a.x * b.x + a.y * b.y + a.z * b.z + a.w * b.w;
#pragma unroll
        for (int off = 1; off < 64; off <<= 1) s += __shfl_xor(s, off);
        if (l == 0) dots[m] = s;
    }
}

// Kernel 2: symmetric fused Gram (MX-fp8). 128x128 tile, 4 waves (2x2 of 64x64),
// BK=128 (2 rounds), mfma_scale 16x16x128 with unit scales. acc = 256*cos.
__global__ __launch_bounds__(256) void gram_kernel(const u8* __restrict__ xq,
                                                   float* __restrict__ part) {
    // XCD swizzle: 2080 blocks = 8 * 260 -> each XCD gets a contiguous triangle range
    const int bidr = (int)blockIdx.x;
    const int t = (bidr & 7) * 260 + (bidr >> 3);
    int bi = (int)(0.5f * (129.0f - sqrtf(16641.0f - 8.0f * (float)t)));
    if (bi > 0 && bi * (129 - bi) / 2 > t) --bi;
    if ((bi + 1) * (129 - (bi + 1)) / 2 <= t) ++bi;
    const int bj = bi + (t - bi * (129 - bi) / 2);
    const bool diagblk = (bi == bj);
    const int r0 = bi * 128, c0 = bj * 128;

    __shared__ __align__(16) char smem[32768];
    u8* As = (u8*)smem;             // [128 rows][128 B] granule(16B)-swizzled
    u8* Bs = (u8*)(smem + 16384);

    const int tid = threadIdx.x;
    const int w = tid >> 6, l = tid & 63;
    const int wr = w >> 1, wc = w & 1;

    const f32x4 vzero = {0.f, 0.f, 0.f, 0.f};
    f32x4 acc[4][4];
#pragma unroll
    for (int m = 0; m < 4; ++m)
#pragma unroll
        for (int n = 0; n < 4; ++n) acc[m][n] = vzero;

    // staging: 1 KB per gload_lds (8 rows x 128 B). LDS[row][g] = glob[row][g^(row&7)] (16B granules)
    const int krow = l >> 3;                       // 0..7
    const int kbyte = ((l & 7) ^ krow) * 16;       // swizzled source granule byte
    const int r7 = l & 7;                          // == row&7 for all frag reads below
    const int kq2 = (l >> 4) * 2;                  // frag K-granule base (pre-swizzle)

    for (int ks = 0; ks < 2; ++ks) {
#pragma unroll
        for (int i = 0; i < 4; ++i) {
            const int rr = w * 32 + i * 8;
            const u8* ga = xq + (size_t)(r0 + rr + krow) * DDIM + ks * 128 + kbyte;
            __builtin_amdgcn_global_load_lds(
                (const __attribute__((address_space(1))) u32*)ga,
                (__attribute__((address_space(3))) u32*)(As + rr * 128), 16, 0, 0);
            const u8* gb = xq + (size_t)(c0 + rr + krow) * DDIM + ks * 128 + kbyte;
            __builtin_amdgcn_global_load_lds(
                (const __attribute__((address_space(1))) u32*)gb,
                (__attribute__((address_space(3))) u32*)(Bs + rr * 128), 16, 0, 0);
        }
        __syncthreads();

        i32x8 bfr[4];
#pragma unroll
        for (int m = 0; m < 4; ++m) {
            const u8* rowp = Bs + (wc * 64 + m * 16 + (l & 15)) * 128;
            const i32x4 lo = *reinterpret_cast<const i32x4*>(rowp + ((kq2 ^ r7) << 4));
            const i32x4 hi = *reinterpret_cast<const i32x4*>(rowp + (((kq2 + 1) ^ r7) << 4));
            bfr[m][0] = lo[0]; bfr[m][1] = lo[1]; bfr[m][2] = lo[2]; bfr[m][3] = lo[3];
            bfr[m][4] = hi[0]; bfr[m][5] = hi[1]; bfr[m][6] = hi[2]; bfr[m][7] = hi[3];
        }
#pragma unroll
        for (int n = 0; n < 4; ++n) {
            const u8* rowp = As + (wr * 64 + n * 16 + (l & 15)) * 128;
            const i32x4 lo = *reinterpret_cast<const i32x4*>(rowp + ((kq2 ^ r7) << 4));
            const i32x4 hi = *reinterpret_cast<const i32x4*>(rowp + (((kq2 + 1) ^ r7) << 4));
            i32x8 afr;
            afr[0] = lo[0]; afr[1] = lo[1]; afr[2] = lo[2]; afr[3] = lo[3];
            afr[4] = hi[0]; afr[5] = hi[1]; afr[6] = hi[2]; afr[7] = hi[3];
            // swapped operands: D col (lane&15) = A-row r, D row axis = B-row j
#pragma unroll
            for (int m = 0; m < 4; ++m)
                acc[m][n] = __builtin_amdgcn_mfma_scale_f32_16x16x128_f8f6f4(
                    bfr[m], afr, acc[m][n], 0, 0, 0, 0x7F7F7F7F, 0, 0x7F7F7F7F);
        }
        __syncthreads();
    }

    // Layout: r = r0 + wr*64 + n*16 + (l&15); j = c0 + wc*64 + m*16 + (l>>4)*4 + rg
    // cos = acc/256; exp in place (diag -> 1.0)
#pragma unroll
    for (int m = 0; m < 4; ++m)
#pragma unroll
        for (int n = 0; n < 4; ++n)
#pragma unroll
            for (int rg = 0; rg < 4; ++rg) {
                const float e = __expf(acc[m][n][rg] * 0.00390625f);
                if (diagblk) {
                    const int j_loc = wc * 64 + m * 16 + (l >> 4) * 4 + rg;
                    const int r_loc = wr * 64 + n * 16 + (l & 15);
                    acc[m][n][rg] = (j_loc == r_loc) ? 1.0f : e;
                } else {
                    acc[m][n][rg] = e;
                }
            }

    float* cs  = (float*)smem;               // [2 wr][128 j][17 pad]
    float* dsh = (float*)(smem + 24576);     // [2 wc][128 r]

#pragma unroll
    for (int n = 0; n < 4; ++n) {
        float s = 0.f;
#pragma unroll
        for (int m = 0; m < 4; ++m)
#pragma unroll
            for (int rg = 0; rg < 4; ++rg) s += acc[m][n][rg];
        s += __shfl_xor(s, 16);
        s += __shfl_xor(s, 32);
        if (l < 16) dsh[wc * 128 + wr * 64 + n * 16 + l] = s;
    }

    if (!diagblk) {
#pragma unroll
        for (int m = 0; m < 4; ++m)
#pragma unroll
            for (int rg = 0; rg < 4; ++rg) {
                const float s = acc[m][0][rg] + acc[m][1][rg] + acc[m][2][rg] + acc[m][3][rg];
                const int j_loc = wc * 64 + m * 16 + (l >> 4) * 4 + rg;
                cs[(wr * 128 + j_loc) * 17 + (l & 15)] = s;
            }
    }
    __syncthreads();

    if (tid < 128) {
        const float den = dsh[tid] + dsh[128 + tid];
        part[(size_t)bj * N_ROWS + r0 + tid] = den;
        if (!diagblk) {
            float c = 0.f;
#pragma unroll
            for (int k = 0; k < 16; ++k)
                c += cs[tid * 17 + k] + cs[(128 + tid) * 17 + k];
            part[(size_t)bi * N_ROWS + c0 + tid] = c;
        }
    }
}

__global__ __launch_bounds__(256) void fin1_kernel(const float* __restrict__ part,
                                                   const float* __restrict__ norms,
                                                   const float* __restrict__ dots,
                                                   float* __restrict__ bsum) {
    const int b = blockIdx.x, t = threadIdx.x;
    const int r = b * 256 + t;
    float den = 0.f;
#pragma unroll 8
    for (int bj = 0; bj < 64; ++bj) den += part[(size_t)bj * N_ROWS + r];
    float local = logf(den);
    if (t < 128) {
        const int m = b * 128 + t;
        local -= 2.0f * dots[m] / (norms[m] * norms[m + HALF]);
    }
#pragma unroll
    for (int off = 1; off < 64; off <<= 1) local += __shfl_xor(local, off);
    __shared__ float wsum[4];
    if ((t & 63) == 0) wsum[t >> 6] = local;
    __syncthreads();
    if (t == 0) bsum[b] = wsum[0] + wsum[1] + wsum[2] + wsum[3];
}

__global__ void fin2_kernel(const float* __restrict__ bsum, float* __restrict__ out) {
    const int t = threadIdx.x;
    float v = (t < 32) ? bsum[t] : 0.f;
#pragma unroll
    for (int off = 1; off < 32; off <<= 1) v += __shfl_xor(v, off);
    if (t == 0) out[0] = v / (float)N_ROWS;
}

extern "C" void kernel_launch(void* const* d_in, const int* in_sizes, int n_in,
                              void* d_out, int out_size, void* d_ws, size_t ws_size,
                              hipStream_t stream) {
    const float* x = (const float*)d_in[0];
    float* out = (float*)d_out;
    char* ws = (char*)d_ws;

    u8*    xq    = (u8*)ws;
    float* norms = (float*)(ws + 2097152);
    float* dots  = (float*)(ws + 2129920);
    float* part  = (float*)(ws + 2146304);
    float* bsum  = (float*)(ws + 4243456);

    prep_kernel<<<3072, 256, 0, stream>>>(x, xq, norms, dots);
    gram_kernel<<<(NBLK * (NBLK + 1)) / 2, 256, 0, stream>>>(xq, part);
    fin1_kernel<<<32, 256, 0, stream>>>(part, norms, dots, bsum);
    fin2_kernel<<<1, 64, 0, stream>>>(bsum, out);
}